// Round 1
// baseline (219.357 us; speedup 1.0000x reference)
//
#include <hip/hip_runtime.h>

// Holt-Winters triple exponential smoothing, one thread per series row.
// N=8192 rows, T=2048 steps, P=24 seasonal period (hardcoded: phase pattern
// is statically unrolled in chunks of 24 so the seasonal buffer stays in
// VGPRs -- runtime indexing would spill it to scratch, rule #20).

__global__ __launch_bounds__(256) void hw_forecast_kernel(
    const float* __restrict__ temp,
    const float* __restrict__ alpha,
    const float* __restrict__ beta,
    const float* __restrict__ gamma,
    const float* __restrict__ L0,
    const float* __restrict__ b0,
    const float* __restrict__ S0,
    float* __restrict__ out,
    int N, int T)
{
    const int i = blockIdx.x * blockDim.x + threadIdx.x;
    if (i >= N) return;

    const float a   = alpha[0];
    const float bt  = beta[0];
    const float g   = gamma[0];
    const float oma = 1.0f - a;
    const float omb = 1.0f - bt;
    const float omg = 1.0f - g;

    // Seasonal ring buffer in registers (static indexing only!)
    float buf[24];
    const float* s0row = S0 + (size_t)i * 24;
    #pragma unroll
    for (int k = 0; k < 24; ++k) buf[k] = s0row[k];

    float L = L0[i];
    float b = b0[i];

    const float* xrow = temp + (size_t)i * T;
    float*       orow = out  + (size_t)i * T;

    // out[:,0] = (L0 + b0) * S0[:,0]
    orow[0] = (L + b) * buf[0];

    int t0 = 1;                    // t0 % 24 == 1 invariant throughout
    const int nfull = (T - 1) / 24;
    const int rem   = (T - 1) % 24;

#define HW_STEP(PH, K) { \
    const float x  = xrow[t0 + (K)]; \
    const float s  = buf[PH]; \
    const float Ln = fmaf(a, x - s, oma * (L + b)); \
    const float bn = fmaf(bt, Ln - L, omb * b); \
    const float sn = fmaf(g, x - Ln, omg * s); \
    buf[PH] = sn; \
    orow[t0 + (K)] = (Ln + bn) * sn; \
    L = Ln; b = bn; \
}

    for (int c = 0; c < nfull; ++c) {
        HW_STEP(1, 0)  HW_STEP(2, 1)  HW_STEP(3, 2)  HW_STEP(4, 3)
        HW_STEP(5, 4)  HW_STEP(6, 5)  HW_STEP(7, 6)  HW_STEP(8, 7)
        HW_STEP(9, 8)  HW_STEP(10, 9) HW_STEP(11,10) HW_STEP(12,11)
        HW_STEP(13,12) HW_STEP(14,13) HW_STEP(15,14) HW_STEP(16,15)
        HW_STEP(17,16) HW_STEP(18,17) HW_STEP(19,18) HW_STEP(20,19)
        HW_STEP(21,20) HW_STEP(22,21) HW_STEP(23,22) HW_STEP(0, 23)
        t0 += 24;
    }

    // Remainder (t0 % 24 == 1 still holds): statically-indexed guarded steps.
    if (rem >  0) { HW_STEP(1, 0)  }
    if (rem >  1) { HW_STEP(2, 1)  }
    if (rem >  2) { HW_STEP(3, 2)  }
    if (rem >  3) { HW_STEP(4, 3)  }
    if (rem >  4) { HW_STEP(5, 4)  }
    if (rem >  5) { HW_STEP(6, 5)  }
    if (rem >  6) { HW_STEP(7, 6)  }
    if (rem >  7) { HW_STEP(8, 7)  }
    if (rem >  8) { HW_STEP(9, 8)  }
    if (rem >  9) { HW_STEP(10, 9) }
    if (rem > 10) { HW_STEP(11,10) }
    if (rem > 11) { HW_STEP(12,11) }
    if (rem > 12) { HW_STEP(13,12) }
    if (rem > 13) { HW_STEP(14,13) }
    if (rem > 14) { HW_STEP(15,14) }
    if (rem > 15) { HW_STEP(16,15) }
    if (rem > 16) { HW_STEP(17,16) }
    if (rem > 17) { HW_STEP(18,17) }
    if (rem > 18) { HW_STEP(19,18) }
    if (rem > 19) { HW_STEP(20,19) }
    if (rem > 20) { HW_STEP(21,20) }
    if (rem > 21) { HW_STEP(22,21) }
    if (rem > 22) { HW_STEP(23,22) }
#undef HW_STEP
}

extern "C" void kernel_launch(void* const* d_in, const int* in_sizes, int n_in,
                              void* d_out, int out_size, void* d_ws, size_t ws_size,
                              hipStream_t stream) {
    const float* temp  = (const float*)d_in[0];
    const float* alpha = (const float*)d_in[1];
    const float* beta  = (const float*)d_in[2];
    const float* gamma = (const float*)d_in[3];
    const float* L0    = (const float*)d_in[4];
    const float* b0    = (const float*)d_in[5];
    const float* S0    = (const float*)d_in[6];
    float* out = (float*)d_out;

    const int N = in_sizes[4];          // L0 length
    const int T = in_sizes[0] / N;      // temp is (N, T)

    const int block = 256;
    const int grid  = (N + block - 1) / block;
    hw_forecast_kernel<<<grid, block, 0, stream>>>(
        temp, alpha, beta, gamma, L0, b0, S0, out, N, T);
}

// Round 2
// 57.339 us; speedup vs baseline: 3.8256x; 3.8256x over previous
//
#include <hip/hip_runtime.h>

// Holt-Winters triple exponential smoothing, one thread per series row.
// N=8192 rows, T=2048 steps, P=24 seasonal period.
//
// Latency-bound regime (128 waves on 1024 SIMDs, occupancy capped by N):
//  - state reformulated as (L, c=L+b): critical chain = 2 dependent FMAs/step
//      Ln = fma(oma, c, a*(x-s));  t1 = fma(omb, c, -L)  [parallel]
//      cn = fma(opb, Ln, t1);      out = cn*sn
//  - x prefetched 2 chunks (48 steps) ahead via triple-buffered 24-float
//    register chunks, 6x aligned float4 loads each (~960cy cover vs ~900cy HBM)
//  - outputs buffered 4-wide, stored as aligned float4
//  - ALL array indices compile-time constant (runtime idx -> scratch, rule #20)

__global__ __launch_bounds__(64) void hw_forecast_kernel(
    const float* __restrict__ temp,
    const float* __restrict__ alpha,
    const float* __restrict__ beta,
    const float* __restrict__ gamma,
    const float* __restrict__ L0,
    const float* __restrict__ b0,
    const float* __restrict__ S0,
    float* __restrict__ out,
    int N, int T)
{
    const int i = blockIdx.x * blockDim.x + threadIdx.x;
    if (i >= N) return;

    const float* xrow = temp + (size_t)i * T;
    float*       orow = out  + (size_t)i * T;

    float xh[24], xb0[24], xb1[24], xb2[24];

    // Load one aligned float4 group (guarded, uniform branch).
#define LOADG(B, T0, J) \
    if ((T0) + 4*(J) + 4 <= T) { \
        const float4 v = *reinterpret_cast<const float4*>(xrow + (T0) + 4*(J)); \
        B[4*(J)+0] = v.x; B[4*(J)+1] = v.y; B[4*(J)+2] = v.z; B[4*(J)+3] = v.w; \
    }
#define LOADX(B, T0) { LOADG(B,(T0),0) LOADG(B,(T0),1) LOADG(B,(T0),2) \
                       LOADG(B,(T0),3) LOADG(B,(T0),4) LOADG(B,(T0),5) }

    // Issue the first three chunks' loads ASAP.
    LOADX(xh, 0)
    LOADX(xb0, 24)
    LOADX(xb1, 48)

    // Seasonal ring buffer in registers (static indexing only).
    float buf[24];
    const float* s0row = S0 + (size_t)i * 24;
    #pragma unroll
    for (int k = 0; k < 24; ++k) buf[k] = s0row[k];

    const float a   = alpha[0];
    const float bt  = beta[0];
    const float g   = gamma[0];
    const float oma = 1.0f - a;
    const float omb = 1.0f - bt;
    const float opb = 1.0f + bt;
    const float omg = 1.0f - g;

    float L = L0[i];
    float c = L + b0[i];          // c = L + b

    float og[4];
    og[0] = c * buf[0];           // out[:,0] = (L0+b0)*S0[:,0]

    int t0 = 0;

    // One step at absolute time t = t0 + K; phase = K (t0 % 24 == 0 invariant).
#define HW_STEP(K, B) { \
    const float x   = B[(K)]; \
    const float s   = buf[(K)]; \
    const float Ln  = fmaf(oma, c, a * (x - s)); \
    const float t1  = fmaf(omb, c, -L); \
    const float cn  = fmaf(opb, Ln, t1); \
    const float sn  = fmaf(g, x - Ln, omg * s); \
    buf[(K)] = sn; \
    og[(K) & 3] = cn * sn; \
    if (((K) & 3) == 3) { \
        *reinterpret_cast<float4*>(orow + t0 + (K) - 3) = \
            float4{og[0], og[1], og[2], og[3]}; \
    } \
    L = Ln; c = cn; \
}

#define CHUNK24(B) { \
    HW_STEP(0,B)  HW_STEP(1,B)  HW_STEP(2,B)  HW_STEP(3,B)  \
    HW_STEP(4,B)  HW_STEP(5,B)  HW_STEP(6,B)  HW_STEP(7,B)  \
    HW_STEP(8,B)  HW_STEP(9,B)  HW_STEP(10,B) HW_STEP(11,B) \
    HW_STEP(12,B) HW_STEP(13,B) HW_STEP(14,B) HW_STEP(15,B) \
    HW_STEP(16,B) HW_STEP(17,B) HW_STEP(18,B) HW_STEP(19,B) \
    HW_STEP(20,B) HW_STEP(21,B) HW_STEP(22,B) HW_STEP(23,B) \
    t0 += 24; }

#define TAILSTEP(K, B) if (t0 + (K) < T) HW_STEP(K, B)
#define TAIL24(B) { \
    TAILSTEP(0,B)  TAILSTEP(1,B)  TAILSTEP(2,B)  TAILSTEP(3,B)  \
    TAILSTEP(4,B)  TAILSTEP(5,B)  TAILSTEP(6,B)  TAILSTEP(7,B)  \
    TAILSTEP(8,B)  TAILSTEP(9,B)  TAILSTEP(10,B) TAILSTEP(11,B) \
    TAILSTEP(12,B) TAILSTEP(13,B) TAILSTEP(14,B) TAILSTEP(15,B) \
    TAILSTEP(16,B) TAILSTEP(17,B) TAILSTEP(18,B) TAILSTEP(19,B) \
    TAILSTEP(20,B) TAILSTEP(21,B) TAILSTEP(22,B) TAILSTEP(23,B) }

    // Head: steps t = 1..23 (phase == t), x from xh.
    HW_STEP(1,xh)  HW_STEP(2,xh)  HW_STEP(3,xh)  HW_STEP(4,xh)
    HW_STEP(5,xh)  HW_STEP(6,xh)  HW_STEP(7,xh)  HW_STEP(8,xh)
    HW_STEP(9,xh)  HW_STEP(10,xh) HW_STEP(11,xh) HW_STEP(12,xh)
    HW_STEP(13,xh) HW_STEP(14,xh) HW_STEP(15,xh) HW_STEP(16,xh)
    HW_STEP(17,xh) HW_STEP(18,xh) HW_STEP(19,xh) HW_STEP(20,xh)
    HW_STEP(21,xh) HW_STEP(22,xh) HW_STEP(23,xh)
    t0 = 24;

    // Full 24-step chunks at t0 = 24, 48, ... (nfull = 84 for T=2048).
    const int nfull = (T >= 48) ? (T - 24) / 24 : 0;
    const int ntri  = nfull / 3;

    for (int m = 0; m < ntri; ++m) {
        LOADX(xb2, t0 + 48) CHUNK24(xb0)
        LOADX(xb0, t0 + 48) CHUNK24(xb1)
        LOADX(xb1, t0 + 48) CHUNK24(xb2)
    }
    const int left = nfull - ntri * 3;
    if (left >= 1) { LOADX(xb2, t0 + 48) CHUNK24(xb0) }
    if (left == 2) { LOADX(xb0, t0 + 48) CHUNK24(xb1) }

    // Tail (8 steps for T=2048); next buffer in rotation holds it.
    if (t0 < T) {
        if      (left == 0) TAIL24(xb0)
        else if (left == 1) TAIL24(xb1)
        else                TAIL24(xb2)
    }

#undef HW_STEP
#undef CHUNK24
#undef TAILSTEP
#undef TAIL24
#undef LOADG
#undef LOADX
}

extern "C" void kernel_launch(void* const* d_in, const int* in_sizes, int n_in,
                              void* d_out, int out_size, void* d_ws, size_t ws_size,
                              hipStream_t stream) {
    const float* temp  = (const float*)d_in[0];
    const float* alpha = (const float*)d_in[1];
    const float* beta  = (const float*)d_in[2];
    const float* gamma = (const float*)d_in[3];
    const float* L0    = (const float*)d_in[4];
    const float* b0    = (const float*)d_in[5];
    const float* S0    = (const float*)d_in[6];
    float* out = (float*)d_out;

    const int N = in_sizes[4];          // L0 length
    const int T = in_sizes[0] / N;      // temp is (N, T)

    const int block = 64;               // 1 wave/block -> spread across 128 CUs
    const int grid  = (N + block - 1) / block;
    hw_forecast_kernel<<<grid, block, 0, stream>>>(
        temp, alpha, beta, gamma, L0, b0, S0, out, N, T);
}